// Round 2
// baseline (616.526 us; speedup 1.0000x reference)
//
#include <hip/hip_runtime.h>

// LiquidLoRA (fp32 I/O): out[s,o] = 2 * sum_r (sum_i x[s,i]*A[r,i]) * Beff[o,r]
// Kernel A: liquid dynamics in fp32 VALU -> Beff bf16 in d_ws; also pre-converts
//           lora_A -> bf16 (abf).
// Kernel B v3: M_blk=16, 256 threads (4 waves), grid 1024 -> 4 blocks/CU.
//   Phase 1: only x staged in LDS (bf16); A-fragments streamed from L2 directly
//            into MFMA B-operands (prefetched one iter ahead).
//   Phase 2: ZERO barriers / ZERO LDS in the loop — t hi/lo fragments hoisted to
//            registers once, beff fragments from L2, direct global stores
//            (4x64B full-cache-line segments per store).
// Roofline: ~408 MB real HBM traffic (x partly L3-resident) -> ~65 us floor.

typedef __attribute__((ext_vector_type(8))) short short8;
typedef __attribute__((ext_vector_type(4))) short short4_t;
typedef __attribute__((ext_vector_type(4))) float f32x4;

static __device__ __forceinline__ unsigned short f2bf(float f) {
    unsigned int x;
    __builtin_memcpy(&x, &f, 4);
    x += 0x7fffu + ((x >> 16) & 1);   // round-to-nearest-even
    return (unsigned short)(x >> 16);
}
static __device__ __forceinline__ float bf2f(unsigned short u) {
    unsigned int x = ((unsigned int)u) << 16;
    float f;
    __builtin_memcpy(&f, &x, 4);
    return f;
}

// ---------------- Kernel A: liquid dynamics (fp32) -> Beff [4096][64] bf16 ----
// grid 256 x block 256. Block = 16 O-rows; thread (row, cg) owns 4 cols.
// Preamble: each thread also converts 4 elements of lora_A -> abf (bf16).
__global__ __launch_bounds__(256) void liquid_kernel(
    const float* __restrict__ loraB,    // [4096][64]
    const float* __restrict__ hiddenB,  // [4096][64]
    const float* __restrict__ Wg,       // [64][128]
    const float* __restrict__ bg,       // [64]
    const float* __restrict__ Wt,       // [64][128]
    const float* __restrict__ bt,       // [64]
    const float* __restrict__ loraA,    // [64][4096]
    unsigned short* __restrict__ beff,  // [4096][64] bf16
    unsigned short* __restrict__ abf)   // [64][4096] bf16
{
    // ---- A -> bf16 (262144 elems = 256 blocks * 256 threads * 4) ----
    {
        const int idx = (blockIdx.x * 256 + threadIdx.x) * 4;
        f32x4 a = *(const f32x4*)&loraA[idx];
        short4_t ab;
#pragma unroll
        for (int j = 0; j < 4; ++j) ab[j] = (short)f2bf(a[j]);
        *(short4_t*)&abf[idx] = ab;
    }

    __shared__ __align__(16) float inp[16][132];   // [target(64) | h(64)], pad
    const int tid = threadIdx.x;
    const int row = tid >> 4;       // 0..15
    const int cg  = tid & 15;       // 0..15
    const int orow = blockIdx.x * 16 + row;
    const int c0 = cg * 4;

    float tgt[4], h[4], bgv[4], btv[4];
#pragma unroll
    for (int i = 0; i < 4; ++i) {
        tgt[i] = loraB[orow * 64 + c0 + i];
        h[i]   = hiddenB[orow * 64 + c0 + i];
        bgv[i] = bg[c0 + i];
        btv[i] = bt[c0 + i];
        inp[row][c0 + i] = tgt[i];     // target half, written once
    }
    for (int step = 0; step < 3; ++step) {
#pragma unroll
        for (int i = 0; i < 4; ++i) inp[row][64 + c0 + i] = h[i];
        __syncthreads();
        float dg[4], dt_[4];
#pragma unroll
        for (int c = 0; c < 4; ++c) { dg[c] = bgv[c]; dt_[c] = btv[c]; }
        for (int k = 0; k < 128; k += 4) {
            f32x4 iv = *(f32x4*)&inp[row][k];
#pragma unroll
            for (int c = 0; c < 4; ++c) {
                f32x4 wgv = *(const f32x4*)&Wg[(c0 + c) * 128 + k];
                f32x4 wtv = *(const f32x4*)&Wt[(c0 + c) * 128 + k];
                dg[c]  += iv[0]*wgv[0] + iv[1]*wgv[1] + iv[2]*wgv[2] + iv[3]*wgv[3];
                dt_[c] += iv[0]*wtv[0] + iv[1]*wtv[1] + iv[2]*wtv[2] + iv[3]*wtv[3];
            }
        }
#pragma unroll
        for (int c = 0; c < 4; ++c) {
            float f   = 1.f / (1.f + __expf(-dg[c]));
            float tau = 0.1f + 9.9f / (1.f + __expf(-dt_[c]));
            float a   = 1.f / tau + f;
            float dec = __expf(-a * 0.1f);
            h[c] = h[c] * dec + (f / a) * tgt[c] * (1.f - dec);
        }
        __syncthreads();   // h-half writes of next step wait for all dot reads
    }
#pragma unroll
    for (int i = 0; i < 4; ++i)
        beff[orow * 64 + c0 + i] = f2bf(h[i]);
}

// ---------------- Kernel B: out = 2 * (x @ A^T) @ Beff^T ----------------
// grid 1024 x block 256 (4 waves), M_blk=16 -> 4 blocks/CU.
__global__ __launch_bounds__(256, 4) void lora_gemm_kernel(
    const float* __restrict__ x,             // [16384][4096]
    const unsigned short* __restrict__ abf,  // [64][4096] bf16
    const unsigned short* __restrict__ beff, // [4096][64] bf16
    float* __restrict__ out)                 // [16384][4096]
{
    __shared__ __align__(16) unsigned short xs[16 * 136];  // x tile bf16, +pad
    __shared__ __align__(16) unsigned short tsh[16 * 72];  // t hi
    __shared__ __align__(16) unsigned short tsl[16 * 72];  // t lo

    const int tid  = threadIdx.x;
    const int lane = tid & 63;
    const int w    = tid >> 6;       // wave 0..3
    const int q    = lane >> 4;      // 0..3
    const int ln   = lane & 15;      // 0..15
    const int m0   = blockIdx.x * 16;

    // x staging coords: 512 f32x4 chunks per 16x128 tile -> 2 per thread
    const int sr = tid >> 5;               // rows 0..7 (i=0), +8 (i=1)
    const int sc = (tid & 31) * 4;         // col group

    // ---- phase 1: t = x_blk @ A^T ----
    // wave w owns A rows w*16..w*16+15; A-fragments direct from L2.
    const int nrow = w * 16 + ln;
    const float* xp0 = &x[(size_t)(m0 + sr) * 4096 + sc];
    const float* xp1 = &x[(size_t)(m0 + sr + 8) * 4096 + sc];
    const unsigned short* ap = &abf[(size_t)nrow * 4096 + q * 8];

    f32x4 xc0 = *(const f32x4*)xp0;
    f32x4 xc1 = *(const f32x4*)xp1;
    short8 ac[4];
#pragma unroll
    for (int kk = 0; kk < 4; ++kk) ac[kk] = *(const short8*)(ap + kk * 32);

    f32x4 acc = (f32x4){0.f, 0.f, 0.f, 0.f};

    for (int it = 0; it < 32; ++it) {
        f32x4 xn0, xn1; short8 an[4];
        if (it < 31) {                      // issue next tile's loads NOW
            const int k = (it + 1) * 128;
            xn0 = *(const f32x4*)(xp0 + k);
            xn1 = *(const f32x4*)(xp1 + k);
#pragma unroll
            for (int kk = 0; kk < 4; ++kk)
                an[kk] = *(const short8*)(ap + k + kk * 32);
        }
        __syncthreads();                    // prev iter's xs reads done
        {
            short4_t b0, b1;
#pragma unroll
            for (int j = 0; j < 4; ++j) {
                b0[j] = (short)f2bf(xc0[j]);
                b1[j] = (short)f2bf(xc1[j]);
            }
            *(short4_t*)&xs[sr * 136 + sc]       = b0;
            *(short4_t*)&xs[(sr + 8) * 136 + sc] = b1;
        }
        __syncthreads();
#pragma unroll
        for (int kk = 0; kk < 4; ++kk) {
            short8 xf = *(short8*)&xs[ln * 136 + kk * 32 + q * 8];
            acc = __builtin_amdgcn_mfma_f32_16x16x32_bf16(xf, ac[kk], acc, 0, 0, 0);
        }
        if (it < 31) {
            xc0 = xn0; xc1 = xn1;
#pragma unroll
            for (int kk = 0; kk < 4; ++kk) ac[kk] = an[kk];
        }
    }

    // park t as hi+lo bf16 (error ~2^-16); row = q*4+r, col = w*16+ln
#pragma unroll
    for (int r = 0; r < 4; ++r) {
        float v = acc[r];
        unsigned short hh = f2bf(v);
        tsh[(q * 4 + r) * 72 + w * 16 + ln] = hh;
        tsl[(q * 4 + r) * 72 + w * 16 + ln] = f2bf(v - bf2f(hh));
    }
    __syncthreads();

    // hoist t fragments to registers: A-operand row=ln, k=kk+q*8
    short8 ah0 = *(short8*)&tsh[ln * 72 + q * 8];
    short8 ah1 = *(short8*)&tsh[ln * 72 + 32 + q * 8];
    short8 al0 = *(short8*)&tsl[ln * 72 + q * 8];
    short8 al1 = *(short8*)&tsl[ln * 72 + 32 + q * 8];

    // ---- phase 2: out_blk = 2 * t @ Beff^T — no barriers, no LDS ----
    // wave w owns out cols (o0 + w*16 + ln); o0 steps by 64.
    const int oc = w * 16;
    const unsigned short* bp = &beff[(size_t)(oc + ln) * 64 + q * 8];
    const size_t orow0 = (size_t)(m0 + q * 4) * 4096 + oc + ln;

    short8 bc0 = *(const short8*)bp;
    short8 bc1 = *(const short8*)(bp + 32);

    for (int it = 0; it < 64; ++it) {
        short8 bn0, bn1;
        if (it < 63) {                      // next beff chunk (L2-resident)
            bn0 = *(const short8*)(bp + (size_t)(it + 1) * 4096);
            bn1 = *(const short8*)(bp + (size_t)(it + 1) * 4096 + 32);
        }
        f32x4 a2 = (f32x4){0.f, 0.f, 0.f, 0.f};
        a2 = __builtin_amdgcn_mfma_f32_16x16x32_bf16(ah0, bc0, a2, 0, 0, 0);
        a2 = __builtin_amdgcn_mfma_f32_16x16x32_bf16(al0, bc0, a2, 0, 0, 0);
        a2 = __builtin_amdgcn_mfma_f32_16x16x32_bf16(ah1, bc1, a2, 0, 0, 0);
        a2 = __builtin_amdgcn_mfma_f32_16x16x32_bf16(al1, bc1, a2, 0, 0, 0);
        const int o0 = it * 64;
#pragma unroll
        for (int r = 0; r < 4; ++r)
            out[orow0 + (size_t)r * 4096 + o0] = a2[r] * 2.0f;
        if (it < 63) { bc0 = bn0; bc1 = bn1; }
    }
}

extern "C" void kernel_launch(void* const* d_in, const int* in_sizes, int n_in,
                              void* d_out, int out_size, void* d_ws, size_t ws_size,
                              hipStream_t stream) {
    const float* x       = (const float*)d_in[0];
    const float* loraA   = (const float*)d_in[1];
    const float* loraB   = (const float*)d_in[2];
    const float* hiddenB = (const float*)d_in[3];
    const float* Wg      = (const float*)d_in[4];
    const float* bg      = (const float*)d_in[5];
    const float* Wt      = (const float*)d_in[6];
    const float* bt      = (const float*)d_in[7];
    float* out = (float*)d_out;
    unsigned short* beff = (unsigned short*)d_ws;      // 4096*64 bf16 = 512 KB
    unsigned short* abf  = beff + 4096 * 64;           // 64*4096 bf16 = 512 KB

    hipLaunchKernelGGL(liquid_kernel, dim3(256), dim3(256), 0, stream,
                       loraB, hiddenB, Wg, bg, Wt, bt, loraA, beff, abf);
    hipLaunchKernelGGL(lora_gemm_kernel, dim3(1024), dim3(256), 0, stream,
                       x, abf, beff, out);
}